// Round 1
// baseline (438.401 us; speedup 1.0000x reference)
//
#include <hip/hip_runtime.h>
#include <hip/hip_bf16.h>
#include <math.h>

typedef __attribute__((ext_vector_type(4))) float f32x4;
typedef __attribute__((ext_vector_type(8))) short short8;

#define DMODEL 768
#define NH 12
#define HD 64
#define DFF 3072

__device__ __forceinline__ short f2bf(float f) {
    union { float f; unsigned int u; } c; c.f = f;
    unsigned int r = c.u + 0x7FFFu + ((c.u >> 16) & 1u);
    return (short)(r >> 16);
}

__device__ __forceinline__ void gload16(const void* g, void* l) {
    __builtin_amdgcn_global_load_lds((const __attribute__((address_space(1))) void*)g,
                                     (__attribute__((address_space(3))) void*)l, 16, 0, 0);
}

// ---------------- weight transpose + cast: src [K][Nn] f32 -> dst [Nn][K] bf16 ----------------
__global__ __launch_bounds__(256) void transpose_cast(const float* __restrict__ src,
                                                      short* __restrict__ dst, int K, int Nn) {
    __shared__ float tile[32][33];
    const int n0 = blockIdx.x * 32, k0 = blockIdx.y * 32;
    const int tx = threadIdx.x & 31, ty = threadIdx.x >> 5;  // 32 x 8
    #pragma unroll
    for (int i = ty; i < 32; i += 8) {
        int k = k0 + i, n = n0 + tx;
        tile[i][tx] = (k < K && n < Nn) ? src[(size_t)k * Nn + n] : 0.f;
    }
    __syncthreads();
    #pragma unroll
    for (int i = ty; i < 32; i += 8) {
        int n = n0 + i, k = k0 + tx;
        if (n < Nn && k < K) dst[(size_t)n * K + k] = f2bf(tile[tx][i]);
    }
}

__global__ void concat_bias(const float* __restrict__ bq, const float* __restrict__ bk,
                            const float* __restrict__ bv, float* __restrict__ out) {
    int i = blockIdx.x * 256 + threadIdx.x;
    if (i < 2304) out[i] = (i < 768) ? bq[i] : (i < 1536 ? bk[i - 768] : bv[i - 1536]);
}

// ---------------- row LayerNorm over D=768, out bf16 ----------------
__global__ __launch_bounds__(256) void ln_rows(const float* __restrict__ x, const float* __restrict__ g,
                                               const float* __restrict__ bb, short* __restrict__ out, int M) {
    __shared__ float red[8];
    const int row = blockIdx.x;
    const int tid = threadIdx.x;
    const float* xr = x + (size_t)row * DMODEL;
    float v[3];
    #pragma unroll
    for (int j = 0; j < 3; j++) v[j] = xr[tid + j * 256];
    float s = v[0] + v[1] + v[2];
    #pragma unroll
    for (int mk = 32; mk; mk >>= 1) s += __shfl_xor(s, mk);
    if ((tid & 63) == 0) red[tid >> 6] = s;
    __syncthreads();
    const float mean = (red[0] + red[1] + red[2] + red[3]) * (1.0f / 768.0f);
    float sq = 0.f;
    #pragma unroll
    for (int j = 0; j < 3; j++) { float d = v[j] - mean; sq += d * d; }
    #pragma unroll
    for (int mk = 32; mk; mk >>= 1) sq += __shfl_xor(sq, mk);
    if ((tid & 63) == 0) red[4 + (tid >> 6)] = sq;
    __syncthreads();
    const float var = (red[4] + red[5] + red[6] + red[7]) * (1.0f / 768.0f);
    const float rstd = rsqrtf(var + 1e-5f);
    short* orow = out + (size_t)row * DMODEL;
    #pragma unroll
    for (int j = 0; j < 3; j++) {
        int col = tid + j * 256;
        orow[col] = f2bf((v[j] - mean) * rstd * g[col] + bb[col]);
    }
}

// ---------------- per-head qk-norm + layout to [B,H,N,64] bf16 ----------------
__global__ __launch_bounds__(256) void qkv_norm(const float* __restrict__ qkv,
        const float* __restrict__ qg, const float* __restrict__ qb,
        const float* __restrict__ kg, const float* __restrict__ kb,
        short* __restrict__ Qb, short* __restrict__ Kb, short* __restrict__ Vb, int B, int Nn) {
    const int row = blockIdx.x;           // b*Nn + n
    const int b = row / Nn, n = row % Nn;
    const int w = threadIdx.x >> 6, d = threadIdx.x & 63;
    const float gq = qg[d], bq_ = qb[d], gk = kg[d], bk_ = kb[d];
    const float* base = qkv + (size_t)row * 2304;
    #pragma unroll
    for (int hh = 0; hh < 3; ++hh) {
        int h = w * 3 + hh;
        float qv = base[h * 64 + d];
        float kv = base[768 + h * 64 + d];
        float vv = base[1536 + h * 64 + d];
        float s = qv;
        #pragma unroll
        for (int mk = 32; mk; mk >>= 1) s += __shfl_xor(s, mk);
        float mq = s * (1.0f / 64.0f);
        float dq = qv - mq;
        float s2 = dq * dq;
        #pragma unroll
        for (int mk = 32; mk; mk >>= 1) s2 += __shfl_xor(s2, mk);
        float qn = dq * rsqrtf(s2 * (1.0f / 64.0f) + 1e-5f) * gq + bq_;
        float sk = kv;
        #pragma unroll
        for (int mk = 32; mk; mk >>= 1) sk += __shfl_xor(sk, mk);
        float mk_ = sk * (1.0f / 64.0f);
        float dk = kv - mk_;
        float sk2 = dk * dk;
        #pragma unroll
        for (int mk = 32; mk; mk >>= 1) sk2 += __shfl_xor(sk2, mk);
        float kn = dk * rsqrtf(sk2 * (1.0f / 64.0f) + 1e-5f) * gk + bk_;
        size_t off = (((size_t)b * NH + h) * Nn + n) * HD + d;
        Qb[off] = f2bf(qn);
        Kb[off] = f2bf(kn);
        Vb[off] = f2bf(vv);
    }
}

// ---------------- GEMM: C[M,Nn] = A[M,K](bf16) * Bt[Nn,K]^T(bf16) + epilogue ----------------
// EPI 0: C f32 = acc + bias[col]
// EPI 1: C f32 = acc + bias[col] + res[row,col]
// EPI 2: C bf16 = gelu(acc + bias[col])   (exact gelu)
template<int EPI>
__global__ __launch_bounds__(256) void gemm_bt(const short* __restrict__ A, const short* __restrict__ Bt,
        const float* __restrict__ bias, const float* __restrict__ res, void* __restrict__ Cv,
        int M, int Nn, int K) {
    __shared__ short As[4096];  // [128][32]
    __shared__ short Bs[4096];
    const int m0 = blockIdx.x * 128, n0 = blockIdx.y * 128;
    const int tid = threadIdx.x, w = tid >> 6, lane = tid & 63, g = lane >> 4, cl = lane & 15;
    const int wm = w >> 1, wn = w & 1;
    f32x4 acc[4][4];
    #pragma unroll
    for (int a = 0; a < 4; a++)
        #pragma unroll
        for (int b2 = 0; b2 < 4; b2++) acc[a][b2] = (f32x4){0.f, 0.f, 0.f, 0.f};
    const int rA = lane >> 2;        // 0..15 rows within chunk
    const int kA = (lane & 3) * 8;   // bf16 elems within row
    for (int kk = 0; kk < K; kk += 32) {
        #pragma unroll
        for (int cc = 0; cc < 2; ++cc) {
            int c = 2 * w + cc;
            int arow = m0 + c * 16 + rA; if (arow >= M) arow = M - 1;
            gload16(A + (size_t)arow * K + kk + kA, &As[c * 512]);
            int brow = n0 + c * 16 + rA;
            gload16(Bt + (size_t)brow * K + kk + kA, &Bs[c * 512]);
        }
        __syncthreads();
        short8 af[4], bf[4];
        #pragma unroll
        for (int mi = 0; mi < 4; mi++) af[mi] = *(const short8*)&As[(wm * 64 + mi * 16 + cl) * 32 + g * 8];
        #pragma unroll
        for (int ni = 0; ni < 4; ni++) bf[ni] = *(const short8*)&Bs[(wn * 64 + ni * 16 + cl) * 32 + g * 8];
        #pragma unroll
        for (int mi = 0; mi < 4; mi++)
            #pragma unroll
            for (int ni = 0; ni < 4; ni++)
                acc[mi][ni] = __builtin_amdgcn_mfma_f32_16x16x32_bf16(af[mi], bf[ni], acc[mi][ni], 0, 0, 0);
        __syncthreads();
    }
    #pragma unroll
    for (int ni = 0; ni < 4; ++ni) {
        int col = n0 + wn * 64 + ni * 16 + cl;
        float bi = bias[col];
        #pragma unroll
        for (int mi = 0; mi < 4; ++mi) {
            int rb = m0 + wm * 64 + mi * 16 + 4 * g;
            #pragma unroll
            for (int r = 0; r < 4; ++r) {
                int row = rb + r;
                if (row < M) {
                    float vv = acc[mi][ni][r] + bi;
                    if (EPI == 1) vv += res[(size_t)row * Nn + col];
                    if (EPI == 2) {
                        float ge = 0.5f * vv * (1.0f + erff(vv * 0.70710678118654752f));
                        ((short*)Cv)[(size_t)row * Nn + col] = f2bf(ge);
                    } else {
                        ((float*)Cv)[(size_t)row * Nn + col] = vv;
                    }
                }
            }
        }
    }
}

// ---------------- flash attention with 2-D ALiBi bias ----------------
// grid: (ceil(N/64), H, B), block 256. Wave w handles 16 q rows.
__global__ __launch_bounds__(256) void attn_kernel(
        const short* __restrict__ Qb, const short* __restrict__ Kb, const short* __restrict__ Vb,
        const float* __restrict__ positions, const float* __restrict__ patch_sizes,
        const int* __restrict__ nregp, short* __restrict__ Ob, int Nn) {
    __shared__ short Vt[64][40];       // V-tile transposed, padded stride 40
    __shared__ short Pl[4][16][40];    // per-wave P tile
    const int qt = blockIdx.x, h = blockIdx.y, b = blockIdx.z;
    const int tid = threadIdx.x, w = tid >> 6, lane = tid & 63, g = lane >> 4, cl = lane & 15;
    const int nreg = nregp[0];
    const float slope = (h < 8) ? exp2f(-(float)(h + 1)) : exp2f(-0.5f - (float)(h - 8));
    const float inv_ps = 1.0f / fmaxf(patch_sizes[b], 1e-6f);
    const size_t bh = ((size_t)b * NH + h) * (size_t)Nn;
    const int q0 = qt * 64 + w * 16;

    int qr = q0 + cl; if (qr > Nn - 1) qr = Nn - 1;
    const short* qptr = Qb + (bh + qr) * HD;
    short8 qf0 = *(const short8*)(qptr + 8 * g);
    short8 qf1 = *(const short8*)(qptr + 32 + 8 * g);

    float qpx[4], qpy[4], keepq[4];
    int qi[4];
    #pragma unroll
    for (int i = 0; i < 4; i++) {
        qi[i] = q0 + 4 * g + i;
        int qc = qi[i] < Nn ? qi[i] : Nn - 1;
        qpx[i] = positions[((size_t)b * Nn + qc) * 2 + 0];
        qpy[i] = positions[((size_t)b * Nn + qc) * 2 + 1];
        bool spec = (qc == 0) || (qc >= 1 && qc < 1 + nreg);
        keepq[i] = spec ? 0.f : 1.f;
    }

    f32x4 o[4];
    #pragma unroll
    for (int c2 = 0; c2 < 4; c2++) o[c2] = (f32x4){0.f, 0.f, 0.f, 0.f};
    float lsum[4] = {0.f, 0.f, 0.f, 0.f};
    float mrun[4] = {-1e30f, -1e30f, -1e30f, -1e30f};

    const int ktiles = (Nn + 31) / 32;
    for (int kt = 0; kt < ktiles; ++kt) {
        const int kv0 = kt * 32;
        __syncthreads();   // protect Vt from previous iteration's readers
        {
            int vr = tid >> 3;            // 0..31
            int vc0 = (tid & 7) * 8;      // 0..56
            int krow = kv0 + vr; if (krow > Nn - 1) krow = Nn - 1;
            short8 vv = *(const short8*)(Vb + (bh + krow) * HD + vc0);
            #pragma unroll
            for (int j = 0; j < 8; j++) Vt[vc0 + j][vr] = vv[j];
        }
        __syncthreads();

        f32x4 sh[2];
        #pragma unroll
        for (int half = 0; half < 2; ++half) {
            int kc = kv0 + half * 16 + cl;
            int kcc = kc < Nn ? kc : Nn - 1;
            const short* kp = Kb + (bh + kcc) * HD;
            short8 kf0 = *(const short8*)(kp + 8 * g);
            short8 kf1 = *(const short8*)(kp + 32 + 8 * g);
            f32x4 z = (f32x4){0.f, 0.f, 0.f, 0.f};
            f32x4 s = __builtin_amdgcn_mfma_f32_16x16x32_bf16(qf0, kf0, z, 0, 0, 0);
            s = __builtin_amdgcn_mfma_f32_16x16x32_bf16(qf1, kf1, s, 0, 0, 0);
            float kpx = positions[((size_t)b * Nn + kcc) * 2 + 0];
            float kpy = positions[((size_t)b * Nn + kcc) * 2 + 1];
            bool spec = (kcc == 0) || (kcc >= 1 && kcc < 1 + nreg);
            float keepk = spec ? 0.f : 1.f;
            bool valid = (kc < Nn);
            #pragma unroll
            for (int i = 0; i < 4; i++) {
                float dx = qpx[i] - kpx, dy = qpy[i] - kpy;
                float bias = -slope * sqrtf(dx * dx + dy * dy) * inv_ps * keepq[i] * keepk;
                float sv = s[i] * 0.125f + bias;
                s[i] = valid ? sv : -1e30f;
            }
            sh[half] = s;
        }
        // online softmax update (rows live in 16-lane groups)
        #pragma unroll
        for (int i = 0; i < 4; i++) {
            float mt = fmaxf(sh[0][i], sh[1][i]);
            #pragma unroll
            for (int mk = 8; mk; mk >>= 1) mt = fmaxf(mt, __shfl_xor(mt, mk));
            float mn = fmaxf(mrun[i], mt);
            float sf = expf(mrun[i] - mn);
            float p0 = expf(sh[0][i] - mn);
            float p1 = expf(sh[1][i] - mn);
            float rs = p0 + p1;
            #pragma unroll
            for (int mk = 8; mk; mk >>= 1) rs += __shfl_xor(rs, mk);
            lsum[i] = lsum[i] * sf + rs;
            mrun[i] = mn;
            #pragma unroll
            for (int c2 = 0; c2 < 4; c2++) o[c2][i] *= sf;
            Pl[w][4 * g + i][cl] = f2bf(p0);
            Pl[w][4 * g + i][16 + cl] = f2bf(p1);
        }
        short8 pf = *(const short8*)&Pl[w][cl][8 * g];
        #pragma unroll
        for (int c2 = 0; c2 < 4; c2++) {
            short8 vf = *(const short8*)&Vt[c2 * 16 + cl][8 * g];
            o[c2] = __builtin_amdgcn_mfma_f32_16x16x32_bf16(pf, vf, o[c2], 0, 0, 0);
        }
    }
    #pragma unroll
    for (int i = 0; i < 4; i++) {
        if (qi[i] < Nn) {
            float inv = 1.0f / lsum[i];
            size_t orow = ((size_t)b * Nn + qi[i]) * DMODEL + (size_t)h * HD;
            #pragma unroll
            for (int c2 = 0; c2 < 4; c2++) {
                Ob[orow + c2 * 16 + cl] = f2bf(o[c2][i] * inv);
            }
        }
    }
}

extern "C" void kernel_launch(void* const* d_in, const int* in_sizes, int n_in,
                              void* d_out, int out_size, void* d_ws, size_t ws_size,
                              hipStream_t stream) {
    const float* x    = (const float*)d_in[0];
    const float* pos  = (const float*)d_in[1];
    const float* psz  = (const float*)d_in[2];
    const int*   nreg = (const int*)d_in[3];
    const float* ln1g = (const float*)d_in[4];
    const float* ln1b = (const float*)d_in[5];
    const float* wq   = (const float*)d_in[6];
    const float* bq   = (const float*)d_in[7];
    const float* wk   = (const float*)d_in[8];
    const float* bk   = (const float*)d_in[9];
    const float* wv   = (const float*)d_in[10];
    const float* bv   = (const float*)d_in[11];
    const float* wo   = (const float*)d_in[12];
    const float* bo   = (const float*)d_in[13];
    const float* qng  = (const float*)d_in[14];
    const float* qnb  = (const float*)d_in[15];
    const float* kng  = (const float*)d_in[16];
    const float* knb  = (const float*)d_in[17];
    const float* ln2g = (const float*)d_in[18];
    const float* ln2b = (const float*)d_in[19];
    const float* w1   = (const float*)d_in[20];
    const float* b1   = (const float*)d_in[21];
    const float* w2   = (const float*)d_in[22];
    const float* b2   = (const float*)d_in[23];

    const int B  = in_sizes[2];
    const int Nn = in_sizes[1] / (2 * B);
    const int M  = B * Nn;

    char* ws = (char*)d_ws;
    size_t off = 0;
    auto alloc = [&](size_t bytes) -> char* {
        char* p = ws + off;
        off += (bytes + 255) & ~(size_t)255;
        return p;
    };
    short* wt_qkv   = (short*)alloc((size_t)2304 * 768 * 2);
    short* wt_o     = (short*)alloc((size_t)768 * 768 * 2);
    short* wt_1     = (short*)alloc((size_t)3072 * 768 * 2);
    short* wt_2     = (short*)alloc((size_t)768 * 3072 * 2);
    float* bias_qkv = (float*)alloc(2304 * 4);
    short* xn       = (short*)alloc((size_t)M * 768 * 2);
    float* qkv      = (float*)alloc((size_t)M * 2304 * 4);
    short* Qb       = (short*)alloc((size_t)M * 768 * 2);
    short* Kb       = (short*)alloc((size_t)M * 768 * 2);
    short* Vb       = (short*)alloc((size_t)M * 768 * 2);
    short* Ob       = (short*)alloc((size_t)M * 768 * 2);
    float* x1       = (float*)alloc((size_t)M * 768 * 4);
    short* xn2      = (short*)alloc((size_t)M * 768 * 2);
    short* hmid     = (short*)alloc((size_t)M * 3072 * 2);

    dim3 blk(256);
    // weight prep
    transpose_cast<<<dim3(24, 24), blk, 0, stream>>>(wq, wt_qkv, 768, 768);
    transpose_cast<<<dim3(24, 24), blk, 0, stream>>>(wk, wt_qkv + 768 * 768, 768, 768);
    transpose_cast<<<dim3(24, 24), blk, 0, stream>>>(wv, wt_qkv + 2 * 768 * 768, 768, 768);
    transpose_cast<<<dim3(24, 24), blk, 0, stream>>>(wo, wt_o, 768, 768);
    transpose_cast<<<dim3(96, 24), blk, 0, stream>>>(w1, wt_1, 768, 3072);
    transpose_cast<<<dim3(24, 96), blk, 0, stream>>>(w2, wt_2, 3072, 768);
    concat_bias<<<9, blk, 0, stream>>>(bq, bk, bv, bias_qkv);

    // LN1
    ln_rows<<<M, blk, 0, stream>>>(x, ln1g, ln1b, xn, M);
    // QKV projection
    gemm_bt<0><<<dim3((M + 127) / 128, 2304 / 128), blk, 0, stream>>>(
        xn, wt_qkv, bias_qkv, nullptr, qkv, M, 2304, 768);
    // qk-norm + relayout
    qkv_norm<<<M, blk, 0, stream>>>(qkv, qng, qnb, kng, knb, Qb, Kb, Vb, B, Nn);
    // attention
    attn_kernel<<<dim3((Nn + 63) / 64, NH, B), blk, 0, stream>>>(
        Qb, Kb, Vb, pos, psz, nreg, Ob, Nn);
    // output projection + residual
    gemm_bt<1><<<dim3((M + 127) / 128, 768 / 128), blk, 0, stream>>>(
        Ob, wt_o, bo, x, x1, M, 768, 768);
    // LN2
    ln_rows<<<M, blk, 0, stream>>>(x1, ln2g, ln2b, xn2, M);
    // MLP up + gelu
    gemm_bt<2><<<dim3((M + 127) / 128, 3072 / 128), blk, 0, stream>>>(
        xn2, wt_1, b1, nullptr, hmid, M, 3072, 768);
    // MLP down + residual -> out
    gemm_bt<1><<<dim3((M + 127) / 128, 768 / 128), blk, 0, stream>>>(
        hmid, wt_2, b2, x1, (float*)d_out, M, 768, 3072);
}

// Round 2
// 427.932 us; speedup vs baseline: 1.0245x; 1.0245x over previous
//
#include <hip/hip_runtime.h>
#include <hip/hip_bf16.h>
#include <math.h>

typedef __attribute__((ext_vector_type(4))) float f32x4;
typedef __attribute__((ext_vector_type(8))) short short8;

#define DMODEL 768
#define NH 12
#define HD 64
#define DFF 3072
#define KVB 64

__device__ __forceinline__ short f2bf(float f) {
    union { float f; unsigned int u; } c; c.f = f;
    unsigned int r = c.u + 0x7FFFu + ((c.u >> 16) & 1u);
    return (short)(r >> 16);
}

__device__ __forceinline__ void gload16(const void* g, void* l) {
    __builtin_amdgcn_global_load_lds((const __attribute__((address_space(1))) void*)g,
                                     (__attribute__((address_space(3))) void*)l, 16, 0, 0);
}

// ---------------- weight transpose + cast: src [K][Nn] f32 -> dst [Nn][K] bf16 ----------------
__global__ __launch_bounds__(256) void transpose_cast(const float* __restrict__ src,
                                                      short* __restrict__ dst, int K, int Nn) {
    __shared__ float tile[32][33];
    const int n0 = blockIdx.x * 32, k0 = blockIdx.y * 32;
    const int tx = threadIdx.x & 31, ty = threadIdx.x >> 5;  // 32 x 8
    #pragma unroll
    for (int i = ty; i < 32; i += 8) {
        int k = k0 + i, n = n0 + tx;
        tile[i][tx] = (k < K && n < Nn) ? src[(size_t)k * Nn + n] : 0.f;
    }
    __syncthreads();
    #pragma unroll
    for (int i = ty; i < 32; i += 8) {
        int n = n0 + i, k = k0 + tx;
        if (n < Nn && k < K) dst[(size_t)n * K + k] = f2bf(tile[tx][i]);
    }
}

__global__ void concat_bias(const float* __restrict__ bq, const float* __restrict__ bk,
                            const float* __restrict__ bv, float* __restrict__ out) {
    int i = blockIdx.x * 256 + threadIdx.x;
    if (i < 2304) out[i] = (i < 768) ? bq[i] : (i < 1536 ? bk[i - 768] : bv[i - 1536]);
}

// ---------------- row LayerNorm over D=768, out bf16 ----------------
__global__ __launch_bounds__(256) void ln_rows(const float* __restrict__ x, const float* __restrict__ g,
                                               const float* __restrict__ bb, short* __restrict__ out, int M) {
    __shared__ float red[8];
    const int row = blockIdx.x;
    const int tid = threadIdx.x;
    const float* xr = x + (size_t)row * DMODEL;
    float v[3];
    #pragma unroll
    for (int j = 0; j < 3; j++) v[j] = xr[tid + j * 256];
    float s = v[0] + v[1] + v[2];
    #pragma unroll
    for (int mk = 32; mk; mk >>= 1) s += __shfl_xor(s, mk);
    if ((tid & 63) == 0) red[tid >> 6] = s;
    __syncthreads();
    const float mean = (red[0] + red[1] + red[2] + red[3]) * (1.0f / 768.0f);
    float sq = 0.f;
    #pragma unroll
    for (int j = 0; j < 3; j++) { float d = v[j] - mean; sq += d * d; }
    #pragma unroll
    for (int mk = 32; mk; mk >>= 1) sq += __shfl_xor(sq, mk);
    if ((tid & 63) == 0) red[4 + (tid >> 6)] = sq;
    __syncthreads();
    const float var = (red[4] + red[5] + red[6] + red[7]) * (1.0f / 768.0f);
    const float rstd = rsqrtf(var + 1e-5f);
    short* orow = out + (size_t)row * DMODEL;
    #pragma unroll
    for (int j = 0; j < 3; j++) {
        int col = tid + j * 256;
        orow[col] = f2bf((v[j] - mean) * rstd * g[col] + bb[col]);
    }
}

// ---------------- per-head qk-norm + layout to [B,H,N,64] bf16 ----------------
__global__ __launch_bounds__(256) void qkv_norm(const float* __restrict__ qkv,
        const float* __restrict__ qg, const float* __restrict__ qb,
        const float* __restrict__ kg, const float* __restrict__ kb,
        short* __restrict__ Qb, short* __restrict__ Kb, short* __restrict__ Vb, int B, int Nn) {
    const int row = blockIdx.x;           // b*Nn + n
    const int b = row / Nn, n = row % Nn;
    const int w = threadIdx.x >> 6, d = threadIdx.x & 63;
    const float gq = qg[d], bq_ = qb[d], gk = kg[d], bk_ = kb[d];
    const float* base = qkv + (size_t)row * 2304;
    #pragma unroll
    for (int hh = 0; hh < 3; ++hh) {
        int h = w * 3 + hh;
        float qv = base[h * 64 + d];
        float kv = base[768 + h * 64 + d];
        float vv = base[1536 + h * 64 + d];
        float s = qv;
        #pragma unroll
        for (int mk = 32; mk; mk >>= 1) s += __shfl_xor(s, mk);
        float mq = s * (1.0f / 64.0f);
        float dq = qv - mq;
        float s2 = dq * dq;
        #pragma unroll
        for (int mk = 32; mk; mk >>= 1) s2 += __shfl_xor(s2, mk);
        float qn = dq * rsqrtf(s2 * (1.0f / 64.0f) + 1e-5f) * gq + bq_;
        float sk = kv;
        #pragma unroll
        for (int mk = 32; mk; mk >>= 1) sk += __shfl_xor(sk, mk);
        float mk_ = sk * (1.0f / 64.0f);
        float dk = kv - mk_;
        float sk2 = dk * dk;
        #pragma unroll
        for (int mk = 32; mk; mk >>= 1) sk2 += __shfl_xor(sk2, mk);
        float kn = dk * rsqrtf(sk2 * (1.0f / 64.0f) + 1e-5f) * gk + bk_;
        size_t off = (((size_t)b * NH + h) * Nn + n) * HD + d;
        Qb[off] = f2bf(qn);
        Kb[off] = f2bf(kn);
        Vb[off] = f2bf(vv);
    }
}

// ---------------- GEMM: C[M,Nn] = A[M,K](bf16) * Bt[Nn,K]^T(bf16) + epilogue ----------------
template<int EPI>
__global__ __launch_bounds__(256) void gemm_bt(const short* __restrict__ A, const short* __restrict__ Bt,
        const float* __restrict__ bias, const float* __restrict__ res, void* __restrict__ Cv,
        int M, int Nn, int K) {
    __shared__ short As[4096];  // [128][32]
    __shared__ short Bs[4096];
    const int m0 = blockIdx.x * 128, n0 = blockIdx.y * 128;
    const int tid = threadIdx.x, w = tid >> 6, lane = tid & 63, g = lane >> 4, cl = lane & 15;
    const int wm = w >> 1, wn = w & 1;
    f32x4 acc[4][4];
    #pragma unroll
    for (int a = 0; a < 4; a++)
        #pragma unroll
        for (int b2 = 0; b2 < 4; b2++) acc[a][b2] = (f32x4){0.f, 0.f, 0.f, 0.f};
    const int rA = lane >> 2;        // 0..15 rows within chunk
    const int kA = (lane & 3) * 8;   // bf16 elems within row
    for (int kk = 0; kk < K; kk += 32) {
        #pragma unroll
        for (int cc = 0; cc < 2; ++cc) {
            int c = 2 * w + cc;
            int arow = m0 + c * 16 + rA; if (arow >= M) arow = M - 1;
            gload16(A + (size_t)arow * K + kk + kA, &As[c * 512]);
            int brow = n0 + c * 16 + rA;
            gload16(Bt + (size_t)brow * K + kk + kA, &Bs[c * 512]);
        }
        __syncthreads();
        short8 af[4], bf[4];
        #pragma unroll
        for (int mi = 0; mi < 4; mi++) af[mi] = *(const short8*)&As[(wm * 64 + mi * 16 + cl) * 32 + g * 8];
        #pragma unroll
        for (int ni = 0; ni < 4; ni++) bf[ni] = *(const short8*)&Bs[(wn * 64 + ni * 16 + cl) * 32 + g * 8];
        #pragma unroll
        for (int mi = 0; mi < 4; mi++)
            #pragma unroll
            for (int ni = 0; ni < 4; ni++)
                acc[mi][ni] = __builtin_amdgcn_mfma_f32_16x16x32_bf16(af[mi], bf[ni], acc[mi][ni], 0, 0, 0);
        __syncthreads();
    }
    #pragma unroll
    for (int ni = 0; ni < 4; ++ni) {
        int col = n0 + wn * 64 + ni * 16 + cl;
        float bi = bias[col];
        #pragma unroll
        for (int mi = 0; mi < 4; ++mi) {
            int rb = m0 + wm * 64 + mi * 16 + 4 * g;
            #pragma unroll
            for (int r = 0; r < 4; ++r) {
                int row = rb + r;
                if (row < M) {
                    float vv = acc[mi][ni][r] + bi;
                    if (EPI == 1) vv += res[(size_t)row * Nn + col];
                    if (EPI == 2) {
                        float ge = 0.5f * vv * (1.0f + erff(vv * 0.70710678118654752f));
                        ((short*)Cv)[(size_t)row * Nn + col] = f2bf(ge);
                    } else {
                        ((float*)Cv)[(size_t)row * Nn + col] = vv;
                    }
                }
            }
        }
    }
}

// ---------------- dist precompute: distm[b][q][k] = dist*keep/ps*log2e ----------------
__global__ __launch_bounds__(256) void dist_kernel(const float* __restrict__ pos,
        const float* __restrict__ psz, const int* __restrict__ nregp,
        float* __restrict__ distm, int Nn) {
    const int k = blockIdx.x * 256 + threadIdx.x;
    const int q = blockIdx.y, b = blockIdx.z;
    if (k >= Nn) return;
    const int nreg = nregp[0];
    const float qx = pos[((size_t)b * Nn + q) * 2], qy = pos[((size_t)b * Nn + q) * 2 + 1];
    const float kx = pos[((size_t)b * Nn + k) * 2], ky = pos[((size_t)b * Nn + k) * 2 + 1];
    const float dx = qx - kx, dy = qy - ky;
    const bool sq_ = q < 1 + nreg || q == 0;
    const bool sk_ = k < 1 + nreg || k == 0;
    const float keep = (sq_ || sk_) ? 0.f : 1.f;
    const float inv_ps = 1.0f / fmaxf(psz[b], 1e-6f);
    distm[((size_t)b * Nn + q) * Nn + k] =
        sqrtf(dx * dx + dy * dy) * inv_ps * keep * 1.4426950408889634f;
}

// ---------------- flash attention, fixed-max softmax (scores bounded by qk-norm) ----------------
// grid: (ceil(N/64), H, B), block 256. Wave w handles 16 q rows, KVB=64 keys/tile.
__global__ __launch_bounds__(256) void attn_kernel(
        const short* __restrict__ Qb, const short* __restrict__ Kb, const short* __restrict__ Vb,
        const float* __restrict__ distm, short* __restrict__ Ob, int Nn) {
    __shared__ short Vt[64][66];       // V^T: [d][kv], stride 66 (conflict-free writes/reads)
    __shared__ short Pl[4][16][72];    // per-wave P tile, stride 72 (b128-aligned reads)
    const int qt = blockIdx.x, h = blockIdx.y, b = blockIdx.z;
    const int tid = threadIdx.x, w = tid >> 6, lane = tid & 63, g = lane >> 4, cl = lane & 15;
    const float slope = (h < 8) ? exp2f(-(float)(h + 1)) : exp2f(-0.5f - (float)(h - 8));
    const size_t bh = ((size_t)b * NH + h) * (size_t)Nn;
    const size_t bq = (size_t)b * Nn;
    const int q0 = qt * 64 + w * 16;
    const float sc2 = 0.125f * 1.4426950408889634f;   // scale * log2(e)

    int qr = q0 + cl; if (qr > Nn - 1) qr = Nn - 1;
    const short* qptr = Qb + (bh + qr) * HD;
    const short8 qf0 = *(const short8*)(qptr + 8 * g);
    const short8 qf1 = *(const short8*)(qptr + 32 + 8 * g);

    int qi[4];
    const float* drow[4];
    #pragma unroll
    for (int i = 0; i < 4; i++) {
        qi[i] = q0 + 4 * g + i;
        int qc = qi[i] < Nn ? qi[i] : Nn - 1;
        drow[i] = distm + (bq + qc) * (size_t)Nn;
    }

    f32x4 o[4];
    #pragma unroll
    for (int c2 = 0; c2 < 4; c2++) o[c2] = (f32x4){0.f, 0.f, 0.f, 0.f};
    float psum[4] = {0.f, 0.f, 0.f, 0.f};

    const int ktiles = (Nn + KVB - 1) / KVB;
    for (int kt = 0; kt < ktiles; ++kt) {
        const int kv0 = kt * KVB;
        __syncthreads();   // protect Vt from previous iteration's readers
        {
            const int kv = tid >> 2, vc0 = (tid & 3) * 16;
            int krow = kv0 + kv; if (krow > Nn - 1) krow = Nn - 1;
            const short* vp = Vb + (bh + krow) * HD + vc0;
            short8 v0 = *(const short8*)vp;
            short8 v1 = *(const short8*)(vp + 8);
            #pragma unroll
            for (int j = 0; j < 8; j++) {
                Vt[vc0 + j][kv] = v0[j];
                Vt[vc0 + 8 + j][kv] = v1[j];
            }
        }
        __syncthreads();

        #pragma unroll
        for (int half = 0; half < 4; ++half) {
            const int kc = kv0 + half * 16 + cl;
            const int kcc = kc < Nn ? kc : Nn - 1;
            const short* kp = Kb + (bh + kcc) * HD;
            const short8 kf0 = *(const short8*)(kp + 8 * g);
            const short8 kf1 = *(const short8*)(kp + 32 + 8 * g);
            f32x4 s = __builtin_amdgcn_mfma_f32_16x16x32_bf16(qf0, kf0, (f32x4){0.f, 0.f, 0.f, 0.f}, 0, 0, 0);
            s = __builtin_amdgcn_mfma_f32_16x16x32_bf16(qf1, kf1, s, 0, 0, 0);
            const bool valid = kc < Nn;
            #pragma unroll
            for (int i = 0; i < 4; i++) {
                float dvv = drow[i][kcc];
                // s2 <= 8*0.125*log2e - 12 < 0 always (||q||=||k||=8 from qk-norm)
                float s2 = valid ? (s[i] * sc2 - slope * dvv - 12.0f) : -1e30f;
                float p = exp2f(s2);
                // truncate to bf16; accumulate the truncated value for consistency
                unsigned int pu = __float_as_uint(p) & 0xffff0000u;
                psum[i] += __uint_as_float(pu);
                Pl[w][4 * g + i][half * 16 + cl] = (short)(pu >> 16);
            }
        }
        #pragma unroll
        for (int ks = 0; ks < 2; ++ks) {
            const short8 pf = *(const short8*)&Pl[w][cl][ks * 32 + 8 * g];
            #pragma unroll
            for (int c2 = 0; c2 < 4; c2++) {
                const int* vi = (const int*)&Vt[c2 * 16 + cl][ks * 32 + 8 * g];
                union { int i4[4]; short8 s8; } u;
                u.i4[0] = vi[0]; u.i4[1] = vi[1]; u.i4[2] = vi[2]; u.i4[3] = vi[3];
                o[c2] = __builtin_amdgcn_mfma_f32_16x16x32_bf16(pf, u.s8, o[c2], 0, 0, 0);
            }
        }
    }
    #pragma unroll
    for (int i = 0; i < 4; i++) {
        float rs = psum[i];
        #pragma unroll
        for (int mk = 8; mk; mk >>= 1) rs += __shfl_xor(rs, mk);
        if (qi[i] < Nn) {
            float inv = 1.0f / rs;
            size_t orow = ((size_t)b * Nn + qi[i]) * DMODEL + (size_t)h * HD;
            #pragma unroll
            for (int c2 = 0; c2 < 4; c2++) {
                Ob[orow + c2 * 16 + cl] = f2bf(o[c2][i] * inv);
            }
        }
    }
}

extern "C" void kernel_launch(void* const* d_in, const int* in_sizes, int n_in,
                              void* d_out, int out_size, void* d_ws, size_t ws_size,
                              hipStream_t stream) {
    const float* x    = (const float*)d_in[0];
    const float* pos  = (const float*)d_in[1];
    const float* psz  = (const float*)d_in[2];
    const int*   nreg = (const int*)d_in[3];
    const float* ln1g = (const float*)d_in[4];
    const float* ln1b = (const float*)d_in[5];
    const float* wq   = (const float*)d_in[6];
    const float* bq   = (const float*)d_in[7];
    const float* wk   = (const float*)d_in[8];
    const float* bk   = (const float*)d_in[9];
    const float* wv   = (const float*)d_in[10];
    const float* bv   = (const float*)d_in[11];
    const float* wo   = (const float*)d_in[12];
    const float* bo   = (const float*)d_in[13];
    const float* qng  = (const float*)d_in[14];
    const float* qnb  = (const float*)d_in[15];
    const float* kng  = (const float*)d_in[16];
    const float* knb  = (const float*)d_in[17];
    const float* ln2g = (const float*)d_in[18];
    const float* ln2b = (const float*)d_in[19];
    const float* w1   = (const float*)d_in[20];
    const float* b1   = (const float*)d_in[21];
    const float* w2   = (const float*)d_in[22];
    const float* b2   = (const float*)d_in[23];

    const int B  = in_sizes[2];
    const int Nn = in_sizes[1] / (2 * B);
    const int M  = B * Nn;

    char* ws = (char*)d_ws;
    size_t off = 0;
    auto alloc = [&](size_t bytes) -> char* {
        char* p = ws + off;
        off += (bytes + 255) & ~(size_t)255;
        return p;
    };
    short* wt_qkv   = (short*)alloc((size_t)2304 * 768 * 2);
    short* wt_o     = (short*)alloc((size_t)768 * 768 * 2);
    short* wt_1     = (short*)alloc((size_t)3072 * 768 * 2);
    short* wt_2     = (short*)alloc((size_t)768 * 3072 * 2);
    float* bias_qkv = (float*)alloc(2304 * 4);
    short* xn       = (short*)alloc((size_t)M * 768 * 2);
    float* qkv      = (float*)alloc((size_t)M * 2304 * 4);
    short* Qb       = (short*)alloc((size_t)M * 768 * 2);
    short* Kb       = (short*)alloc((size_t)M * 768 * 2);
    short* Vb       = (short*)alloc((size_t)M * 768 * 2);
    short* Ob       = (short*)alloc((size_t)M * 768 * 2);
    float* x1       = (float*)alloc((size_t)M * 768 * 4);
    short* xn2      = (short*)alloc((size_t)M * 768 * 2);
    short* hmid     = (short*)alloc((size_t)M * 3072 * 2);
    // distm aliases the qkv f32 buffer (dead after qkv_norm); 16.8MB <= 37.8MB
    float* distm    = qkv;

    dim3 blk(256);
    // weight prep
    transpose_cast<<<dim3(24, 24), blk, 0, stream>>>(wq, wt_qkv, 768, 768);
    transpose_cast<<<dim3(24, 24), blk, 0, stream>>>(wk, wt_qkv + 768 * 768, 768, 768);
    transpose_cast<<<dim3(24, 24), blk, 0, stream>>>(wv, wt_qkv + 2 * 768 * 768, 768, 768);
    transpose_cast<<<dim3(24, 24), blk, 0, stream>>>(wo, wt_o, 768, 768);
    transpose_cast<<<dim3(96, 24), blk, 0, stream>>>(w1, wt_1, 768, 3072);
    transpose_cast<<<dim3(24, 96), blk, 0, stream>>>(w2, wt_2, 3072, 768);
    concat_bias<<<9, blk, 0, stream>>>(bq, bk, bv, bias_qkv);

    // LN1
    ln_rows<<<M, blk, 0, stream>>>(x, ln1g, ln1b, xn, M);
    // QKV projection
    gemm_bt<0><<<dim3((M + 127) / 128, 2304 / 128), blk, 0, stream>>>(
        xn, wt_qkv, bias_qkv, nullptr, qkv, M, 2304, 768);
    // qk-norm + relayout (reads qkv f32)
    qkv_norm<<<M, blk, 0, stream>>>(qkv, qng, qnb, kng, knb, Qb, Kb, Vb, B, Nn);
    // dist precompute (overwrites qkv buffer — dead now)
    dist_kernel<<<dim3((Nn + 255) / 256, Nn, B), blk, 0, stream>>>(pos, psz, nreg, distm, Nn);
    // attention
    attn_kernel<<<dim3((Nn + 63) / 64, NH, B), blk, 0, stream>>>(
        Qb, Kb, Vb, distm, Ob, Nn);
    // output projection + residual
    gemm_bt<1><<<dim3((M + 127) / 128, 768 / 128), blk, 0, stream>>>(
        Ob, wt_o, bo, x, x1, M, 768, 768);
    // LN2
    ln_rows<<<M, blk, 0, stream>>>(x1, ln2g, ln2b, xn2, M);
    // MLP up + gelu
    gemm_bt<2><<<dim3((M + 127) / 128, 3072 / 128), blk, 0, stream>>>(
        xn2, wt_1, b1, nullptr, hmid, M, 3072, 768);
    // MLP down + residual -> out
    gemm_bt<1><<<dim3((M + 127) / 128, 768 / 128), blk, 0, stream>>>(
        hmid, wt_2, b2, x1, (float*)d_out, M, 768, 3072);
}